// Round 1
// baseline (1381.987 us; speedup 1.0000x reference)
//
#include <hip/hip_runtime.h>
#include <math.h>

#define Nn 100000
#define Ee 500000
#define Dd 128
#define Rr 10
#define ND (Nn * Dd)
#define TM 32

__device__ __forceinline__ void atomAddF(float* p, float v) {
    unsafeAtomicAdd(p, v);   // HW global_atomic_add_f32 on gfx950
}

// ---------------- zero fills ----------------
__global__ void kzero(float* p, int n) {
    int i = blockIdx.x * blockDim.x + threadIdx.x;
    int stride = gridDim.x * blockDim.x;
    for (; i < n; i += stride) p[i] = 0.f;
}

__global__ void kzero4(float4* p, int n4) {
    int i = blockIdx.x * blockDim.x + threadIdx.x;
    int stride = gridDim.x * blockDim.x;
    float4 z = make_float4(0.f, 0.f, 0.f, 0.f);
    for (; i < n4; i += stride) p[i] = z;
}

// ---------------- degrees ----------------
__global__ void kdeg(const int* __restrict__ src, const int* __restrict__ dst,
                     float* deg_s, float* deg_d, int ne) {
    int e = blockIdx.x * blockDim.x + threadIdx.x;
    if (e < ne) {
        atomAddF(&deg_s[src[e]], 1.f);
        atomAddF(&deg_d[dst[e]], 1.f);
    }
}

__global__ void kdinv(float* deg_s, float* deg_d, int n) {
    int i = blockIdx.x * blockDim.x + threadIdx.x;
    if (i < n) {
        float a = deg_s[i];
        deg_s[i] = (a > 0.f) ? rsqrtf(a) : 0.f;
        float b = deg_d[i];
        deg_d[i] = (b > 0.f) ? rsqrtf(b) : 0.f;
    }
}

// ---------------- edge aggregation (both directions fused) ----------------
// agg_in[src]  += x[dst]*rel[type] * dinv_s[src]*dinv_s[dst]
// agg_out[dst] += x[src]*rel[type] * dinv_d[dst]*dinv_d[src]
__global__ __launch_bounds__(256) void kedge(
    const int* __restrict__ src, const int* __restrict__ dst, const int* __restrict__ typ,
    const float* __restrict__ x, const float* __restrict__ rel,
    const float* __restrict__ dinv_s, const float* __restrict__ dinv_d,
    float* aggin, float* aggout, int ne) {
    int e = blockIdx.x * 2 + (threadIdx.x >> 7);
    if (e >= ne) return;
    int j = threadIdx.x & 127;
    int s = src[e], d = dst[e], t = typ[e];
    float nin = dinv_s[s] * dinv_s[d];
    float nout = dinv_d[d] * dinv_d[s];
    float rv = rel[t * Dd + j];
    float xd = x[d * Dd + j];
    float xs = x[s * Dd + j];
    atomAddF(&aggin[s * Dd + j], xd * rv * nin);
    atomAddF(&aggout[d * Dd + j], xs * rv * nout);
}

// ---------------- fused 3-way GEMM + bias + BN column stats ----------------
// out = (aggin@Win + aggout@Wout + (x*looprel)@Wloop)/3 + bias
// out may alias aggin (rows are block-local, staged through LDS before write).
__global__ __launch_bounds__(256) void kmm(
    const float* aggin, const float* aggout, const float* xin,
    const float* __restrict__ Win, const float* __restrict__ Wout,
    const float* __restrict__ Wloop,
    const float* __restrict__ looprel, const float* __restrict__ bias,
    float* out, float* colsum, float* colsumsq) {
    __shared__ float sW[Dd * Dd];   // 64 KB, sW[k*128 + j]
    __shared__ float sA[Dd * TM];   // 16 KB, k-major: sA[k*32 + i]
    const int tid = threadIdx.x;
    const int m0 = blockIdx.x * TM;
    const int g = tid >> 5;          // 0..7 row group
    const int i0 = g * 4;            // local row base
    const int c0 = (tid & 31) * 4;   // column base
    float acc[4][4] = {{0.f}};

    for (int p = 0; p < 3; p++) {
        const float* A = (p == 0) ? aggin : ((p == 1) ? aggout : xin);
        const float* W = (p == 0) ? Win : ((p == 1) ? Wout : Wloop);
        __syncthreads();
        {
            // stage A tile (32 rows x 128 k), transposed into sA[k*32+i]
            int row = tid >> 3;         // 0..31
            int k0 = (tid & 7) * 16;    // 0..112
            const float4* Ar = (const float4*)(A + (m0 + row) * Dd + k0);
            float4 v[4];
#pragma unroll
            for (int q = 0; q < 4; q++) v[q] = Ar[q];
            if (p == 2) {
                const float4* Lr = (const float4*)(looprel + k0);
#pragma unroll
                for (int q = 0; q < 4; q++) {
                    float4 lv = Lr[q];
                    v[q].x *= lv.x; v[q].y *= lv.y; v[q].z *= lv.z; v[q].w *= lv.w;
                }
            }
#pragma unroll
            for (int q = 0; q < 4; q++) {
                int k = k0 + q * 4;
                sA[(k + 0) * TM + row] = v[q].x;
                sA[(k + 1) * TM + row] = v[q].y;
                sA[(k + 2) * TM + row] = v[q].z;
                sA[(k + 3) * TM + row] = v[q].w;
            }
            // stage full W (128x128), coalesced float4
            const float4* Wg = (const float4*)W;
            float4* sWv = (float4*)sW;
#pragma unroll
            for (int q = 0; q < 16; q++) sWv[q * 256 + tid] = Wg[q * 256 + tid];
        }
        __syncthreads();
#pragma unroll 4
        for (int k = 0; k < Dd; k++) {
            float4 av = *(const float4*)(sA + k * TM + i0);
            float4 wv = *(const float4*)(sW + k * Dd + c0);
            acc[0][0] += av.x * wv.x; acc[0][1] += av.x * wv.y; acc[0][2] += av.x * wv.z; acc[0][3] += av.x * wv.w;
            acc[1][0] += av.y * wv.x; acc[1][1] += av.y * wv.y; acc[1][2] += av.y * wv.z; acc[1][3] += av.y * wv.w;
            acc[2][0] += av.z * wv.x; acc[2][1] += av.z * wv.y; acc[2][2] += av.z * wv.z; acc[2][3] += av.z * wv.w;
            acc[3][0] += av.w * wv.x; acc[3][1] += av.w * wv.y; acc[3][2] += av.w * wv.z; acc[3][3] += av.w * wv.w;
        }
    }

    // epilogue: scale, bias, store, BN partial sums
    const float inv3 = 1.f / 3.f;
    float4 bv = *(const float4*)(bias + c0);
    float bb[4] = {bv.x, bv.y, bv.z, bv.w};
    float vals[4][4];
#pragma unroll
    for (int r = 0; r < 4; r++) {
#pragma unroll
        for (int c = 0; c < 4; c++) vals[r][c] = acc[r][c] * inv3 + bb[c];
        *(float4*)(out + (m0 + i0 + r) * Dd + c0) =
            make_float4(vals[r][0], vals[r][1], vals[r][2], vals[r][3]);
    }
    __syncthreads();  // done reading sA/sW, reuse sA as reduction scratch
#pragma unroll
    for (int c = 0; c < 4; c++) {
        float s = vals[0][c] + vals[1][c] + vals[2][c] + vals[3][c];
        float s2 = vals[0][c] * vals[0][c] + vals[1][c] * vals[1][c] +
                   vals[2][c] * vals[2][c] + vals[3][c] * vals[3][c];
        sA[g * Dd + c0 + c] = s;
        sA[1024 + g * Dd + c0 + c] = s2;
    }
    __syncthreads();
    if (tid < Dd) {
        float s = 0.f, s2 = 0.f;
#pragma unroll
        for (int g2 = 0; g2 < 8; g2++) {
            s += sA[g2 * Dd + tid];
            s2 += sA[1024 + g2 * Dd + tid];
        }
        atomAddF(&colsum[tid], s);
        atomAddF(&colsumsq[tid], s2);
    }
}

// ---------------- BN stats ----------------
__global__ void kstats(const float* __restrict__ colsum, const float* __restrict__ colsumsq,
                       float* mean, float* rstd) {
    int j = threadIdx.x;
    float m = colsum[j] * (1.f / (float)Nn);
    float v = colsumsq[j] * (1.f / (float)Nn) - m * m;
    mean[j] = m;
    rstd[j] = rsqrtf(v + 1e-5f);
}

// ---------------- normalize + tanh ----------------
__global__ __launch_bounds__(256) void knorm(const float* __restrict__ outb,
                                             const float* __restrict__ mean,
                                             const float* __restrict__ rstd,
                                             float* __restrict__ xn) {
    int idx = blockIdx.x * blockDim.x + threadIdx.x;  // float4 index over ND/4
    int c = (idx & 31) * 4;
    float4 v = ((const float4*)outb)[idx];
    float4 mn = *(const float4*)(mean + c);
    float4 rs = *(const float4*)(rstd + c);
    float4 o;
    o.x = tanhf((v.x - mn.x) * rs.x);
    o.y = tanhf((v.y - mn.y) * rs.y);
    o.z = tanhf((v.z - mn.z) * rs.z);
    o.w = tanhf((v.w - mn.w) * rs.w);
    ((float4*)xn)[idx] = o;
}

// ---------------- relation transform: rn = r @ w ----------------
__global__ void krel(const float* __restrict__ r, const float* __restrict__ w,
                     float* __restrict__ rn) {
    __shared__ float sr[Dd];
    int j = threadIdx.x, row = blockIdx.x;
    sr[j] = r[row * Dd + j];
    __syncthreads();
    float acc = 0.f;
    for (int k = 0; k < Dd; k++) acc += sr[k] * w[k * Dd + j];
    rn[row * Dd + j] = acc;
}

extern "C" void kernel_launch(void* const* d_in, const int* in_sizes, int n_in,
                              void* d_out, int out_size, void* d_ws, size_t ws_size,
                              hipStream_t stream) {
    const float* x0      = (const float*)d_in[0];   // [N,D]
    const float* r0      = (const float*)d_in[1];   // [R,D]
    const float* w_in    = (const float*)d_in[2];   // [L,D,D]
    const float* w_out   = (const float*)d_in[3];
    const float* w_loop  = (const float*)d_in[4];
    const float* w_rel   = (const float*)d_in[5];
    const float* looprel = (const float*)d_in[6];   // [L,1,D]
    const float* bias    = (const float*)d_in[7];   // [L,D]
    const int* esrc = (const int*)d_in[8];
    const int* edst = (const int*)d_in[9];
    const int* etyp = (const int*)d_in[10];
    float* outp = (float*)d_out;

    float* ws = (float*)d_ws;
    float* aggin   = ws;                       // ND
    float* aggout  = ws + (size_t)ND;          // ND  (contiguous with aggin)
    float* x1      = ws + 2 * (size_t)ND;      // ND
    float* deg_s   = ws + 3 * (size_t)ND;      // N
    float* deg_d   = deg_s + Nn;               // N
    float* colsum  = deg_d + Nn;               // 128
    float* colsumsq= colsum + Dd;              // 128
    float* meanb   = colsumsq + Dd;            // 128
    float* rstdb   = meanb + Dd;               // 128
    float* r1      = rstdb + Dd;               // R*D

    // degree norms (edge-list-only, once per call)
    kzero<<<256, 256, 0, stream>>>(deg_s, 2 * Nn);
    kdeg<<<(Ee + 255) / 256, 256, 0, stream>>>(esrc, edst, deg_s, deg_d, Ee);
    kdinv<<<(Nn + 255) / 256, 256, 0, stream>>>(deg_s, deg_d, Nn);

    for (int l = 0; l < 2; l++) {
        const float* xc = l ? x1 : x0;
        const float* rc = l ? r1 : r0;
        float* xn = l ? outp : x1;
        float* rn = l ? (outp + (size_t)ND) : r1;

        kzero4<<<8192, 256, 0, stream>>>((float4*)aggin, 2 * ND / 4);  // aggin+aggout
        kzero<<<1, 256, 0, stream>>>(colsum, 2 * Dd);
        kedge<<<(Ee + 1) / 2, 256, 0, stream>>>(esrc, edst, etyp, xc, rc,
                                                deg_s, deg_d, aggin, aggout, Ee);
        kmm<<<Nn / TM, 256, 0, stream>>>(aggin, aggout, xc,
                                         w_in + l * Dd * Dd, w_out + l * Dd * Dd,
                                         w_loop + l * Dd * Dd, looprel + l * Dd,
                                         bias + l * Dd, aggin /*in-place out*/,
                                         colsum, colsumsq);
        kstats<<<1, Dd, 0, stream>>>(colsum, colsumsq, meanb, rstdb);
        knorm<<<ND / 4 / 256, 256, 0, stream>>>(aggin, meanb, rstdb, xn);
        krel<<<Rr, Dd, 0, stream>>>(rc, w_rel + l * Dd * Dd, rn);
    }
}

// Round 2
// 895.219 us; speedup vs baseline: 1.5437x; 1.5437x over previous
//
#include <hip/hip_runtime.h>
#include <math.h>

#define Nn 100000
#define Ee 500000
#define Dd 128
#define Rr 10
#define ND (Nn * Dd)
#define TM 32
#define SCAN_CHUNK 1024
#define NBLK ((Nn + SCAN_CHUNK - 1) / SCAN_CHUNK)   // 98

__device__ __forceinline__ void atomAddF(float* p, float v) {
    unsafeAtomicAdd(p, v);   // HW global_atomic_add_f32 on gfx950
}

// ---------------- zero fill ----------------
__global__ void kzeroi(int* p, int n) {
    int i = blockIdx.x * blockDim.x + threadIdx.x;
    int stride = gridDim.x * blockDim.x;
    for (; i < n; i += stride) p[i] = 0;
}

__global__ void kzerof(float* p, int n) {
    int i = blockIdx.x * blockDim.x + threadIdx.x;
    int stride = gridDim.x * blockDim.x;
    for (; i < n; i += stride) p[i] = 0.f;
}

// ---------------- histogram (int degrees, both endpoints) ----------------
__global__ void khist(const int* __restrict__ src, const int* __restrict__ dst,
                      int* cnt_s, int* cnt_d, int ne) {
    int e = blockIdx.x * blockDim.x + threadIdx.x;
    if (e < ne) {
        atomicAdd(&cnt_s[src[e]], 1);
        atomicAdd(&cnt_d[dst[e]], 1);
    }
}

__global__ void kdinv(const int* __restrict__ cnt_s, const int* __restrict__ cnt_d,
                      float* dinv_s, float* dinv_d, int n) {
    int i = blockIdx.x * blockDim.x + threadIdx.x;
    if (i < n) {
        int a = cnt_s[i];
        dinv_s[i] = (a > 0) ? rsqrtf((float)a) : 0.f;
        int b = cnt_d[i];
        dinv_d[i] = (b > 0) ? rsqrtf((float)b) : 0.f;
    }
}

// ---------------- exclusive scan (3-phase) ----------------
// phase 1: per-block local exclusive scan of 1024 elems, emit block sum
__global__ __launch_bounds__(256) void kscan1(const int* __restrict__ cnt,
                                              int* off, int* bsum, int n) {
    __shared__ int s[256];
    int tid = threadIdx.x;
    int base = blockIdx.x * SCAN_CHUNK + tid * 4;
    int v[4], sum = 0;
#pragma unroll
    for (int q = 0; q < 4; q++) {
        v[q] = (base + q < n) ? cnt[base + q] : 0;
        sum += v[q];
    }
    s[tid] = sum;
    __syncthreads();
#pragma unroll
    for (int ofs = 1; ofs < 256; ofs <<= 1) {
        int t = (tid >= ofs) ? s[tid - ofs] : 0;
        __syncthreads();
        s[tid] += t;
        __syncthreads();
    }
    if (tid == 255) bsum[blockIdx.x] = s[255];
    int run = s[tid] - sum;   // exclusive base for this thread
#pragma unroll
    for (int q = 0; q < 4; q++) {
        if (base + q < n) off[base + q] = run;
        run += v[q];
    }
}

// phase 2: exclusive scan of block sums (NBLK <= 128), in place; write off[n]=total
__global__ __launch_bounds__(128) void kscan2(int* bsum, int* off, int n, int nb) {
    __shared__ int s[128];
    int tid = threadIdx.x;
    int v = (tid < nb) ? bsum[tid] : 0;
    s[tid] = v;
    __syncthreads();
#pragma unroll
    for (int ofs = 1; ofs < 128; ofs <<= 1) {
        int t = (tid >= ofs) ? s[tid - ofs] : 0;
        __syncthreads();
        s[tid] += t;
        __syncthreads();
    }
    if (tid < nb) bsum[tid] = s[tid] - v;
    if (tid == 127) off[n] = s[127];
}

// phase 3: add block bases
__global__ void kscan3(int* off, const int* __restrict__ bsum, int n) {
    int i = blockIdx.x * blockDim.x + threadIdx.x;
    if (i < n) off[i] += bsum[i >> 10];
}

__global__ void kcopyi(const int* __restrict__ a, int* b, int n) {
    int i = blockIdx.x * blockDim.x + threadIdx.x;
    if (i < n) b[i] = a[i];
}

// ---------------- build CSR adjacency (packed (nbr<<4)|type + norm) ----------------
__global__ void kscatter(const int* __restrict__ src, const int* __restrict__ dst,
                         const int* __restrict__ typ,
                         const float* __restrict__ dinv_s, const float* __restrict__ dinv_d,
                         int* cur_s, int* cur_d,
                         int* pack_s, float* norm_s, int* pack_d, float* norm_d, int ne) {
    int e = blockIdx.x * blockDim.x + threadIdx.x;
    if (e >= ne) return;
    int s = src[e], d = dst[e], t = typ[e];
    int ps = atomicAdd(&cur_s[s], 1);
    pack_s[ps] = (d << 4) | t;
    norm_s[ps] = dinv_s[s] * dinv_s[d];
    int pd = atomicAdd(&cur_d[d], 1);
    pack_d[pd] = (s << 4) | t;
    norm_d[pd] = dinv_d[d] * dinv_d[s];
}

// ---------------- gather-side aggregation: one wave per node ----------------
// agg[n] = sum over incident edges of x[nbr]*rel[type]*norm  (no atomics)
__global__ __launch_bounds__(256) void kgather(
    const int* __restrict__ off, const int* __restrict__ pack,
    const float* __restrict__ nrm, const float* __restrict__ x,
    const float* __restrict__ rel, float* __restrict__ agg) {
    int node = (blockIdx.x << 2) | (threadIdx.x >> 6);
    if (node >= Nn) return;
    int lane = threadIdx.x & 63;
    int b = off[node], e = off[node + 1];
    const float2* x2 = (const float2*)x;
    const float2* r2 = (const float2*)rel;
    float2 acc = make_float2(0.f, 0.f);
    for (int i = b; i < e; i++) {
        int p = pack[i];
        float w = nrm[i];
        int d = p >> 4, t = p & 15;
        float2 xv = x2[d * 64 + lane];
        float2 rv = r2[t * 64 + lane];
        acc.x += xv.x * rv.x * w;
        acc.y += xv.y * rv.y * w;
    }
    ((float2*)agg)[node * 64 + lane] = acc;
}

// ---------------- fused 3-way GEMM + bias + BN column stats ----------------
__global__ __launch_bounds__(256) void kmm(
    const float* aggin, const float* aggout, const float* xin,
    const float* __restrict__ Win, const float* __restrict__ Wout,
    const float* __restrict__ Wloop,
    const float* __restrict__ looprel, const float* __restrict__ bias,
    float* out, float* colsum, float* colsumsq) {
    __shared__ float sW[Dd * Dd];   // 64 KB, sW[k*128 + j]
    __shared__ float sA[Dd * TM];   // 16 KB, k-major: sA[k*32 + i]
    const int tid = threadIdx.x;
    const int m0 = blockIdx.x * TM;
    const int g = tid >> 5;          // 0..7 row group
    const int i0 = g * 4;            // local row base
    const int c0 = (tid & 31) * 4;   // column base
    float acc[4][4] = {{0.f}};

    for (int p = 0; p < 3; p++) {
        const float* A = (p == 0) ? aggin : ((p == 1) ? aggout : xin);
        const float* W = (p == 0) ? Win : ((p == 1) ? Wout : Wloop);
        __syncthreads();
        {
            int row = tid >> 3;         // 0..31
            int k0 = (tid & 7) * 16;    // 0..112
            const float4* Ar = (const float4*)(A + (m0 + row) * Dd + k0);
            float4 v[4];
#pragma unroll
            for (int q = 0; q < 4; q++) v[q] = Ar[q];
            if (p == 2) {
                const float4* Lr = (const float4*)(looprel + k0);
#pragma unroll
                for (int q = 0; q < 4; q++) {
                    float4 lv = Lr[q];
                    v[q].x *= lv.x; v[q].y *= lv.y; v[q].z *= lv.z; v[q].w *= lv.w;
                }
            }
#pragma unroll
            for (int q = 0; q < 4; q++) {
                int k = k0 + q * 4;
                sA[(k + 0) * TM + row] = v[q].x;
                sA[(k + 1) * TM + row] = v[q].y;
                sA[(k + 2) * TM + row] = v[q].z;
                sA[(k + 3) * TM + row] = v[q].w;
            }
            const float4* Wg = (const float4*)W;
            float4* sWv = (float4*)sW;
#pragma unroll
            for (int q = 0; q < 16; q++) sWv[q * 256 + tid] = Wg[q * 256 + tid];
        }
        __syncthreads();
#pragma unroll 4
        for (int k = 0; k < Dd; k++) {
            float4 av = *(const float4*)(sA + k * TM + i0);
            float4 wv = *(const float4*)(sW + k * Dd + c0);
            acc[0][0] += av.x * wv.x; acc[0][1] += av.x * wv.y; acc[0][2] += av.x * wv.z; acc[0][3] += av.x * wv.w;
            acc[1][0] += av.y * wv.x; acc[1][1] += av.y * wv.y; acc[1][2] += av.y * wv.z; acc[1][3] += av.y * wv.w;
            acc[2][0] += av.z * wv.x; acc[2][1] += av.z * wv.y; acc[2][2] += av.z * wv.z; acc[2][3] += av.z * wv.w;
            acc[3][0] += av.w * wv.x; acc[3][1] += av.w * wv.y; acc[3][2] += av.w * wv.z; acc[3][3] += av.w * wv.w;
        }
    }

    const float inv3 = 1.f / 3.f;
    float4 bv = *(const float4*)(bias + c0);
    float bb[4] = {bv.x, bv.y, bv.z, bv.w};
    float vals[4][4];
#pragma unroll
    for (int r = 0; r < 4; r++) {
#pragma unroll
        for (int c = 0; c < 4; c++) vals[r][c] = acc[r][c] * inv3 + bb[c];
        *(float4*)(out + (m0 + i0 + r) * Dd + c0) =
            make_float4(vals[r][0], vals[r][1], vals[r][2], vals[r][3]);
    }
    __syncthreads();
#pragma unroll
    for (int c = 0; c < 4; c++) {
        float s = vals[0][c] + vals[1][c] + vals[2][c] + vals[3][c];
        float s2 = vals[0][c] * vals[0][c] + vals[1][c] * vals[1][c] +
                   vals[2][c] * vals[2][c] + vals[3][c] * vals[3][c];
        sA[g * Dd + c0 + c] = s;
        sA[1024 + g * Dd + c0 + c] = s2;
    }
    __syncthreads();
    if (tid < Dd) {
        float s = 0.f, s2 = 0.f;
#pragma unroll
        for (int g2 = 0; g2 < 8; g2++) {
            s += sA[g2 * Dd + tid];
            s2 += sA[1024 + g2 * Dd + tid];
        }
        atomAddF(&colsum[tid], s);
        atomAddF(&colsumsq[tid], s2);
    }
}

// ---------------- BN stats ----------------
__global__ void kstats(const float* __restrict__ colsum, const float* __restrict__ colsumsq,
                       float* mean, float* rstd) {
    int j = threadIdx.x;
    float m = colsum[j] * (1.f / (float)Nn);
    float v = colsumsq[j] * (1.f / (float)Nn) - m * m;
    mean[j] = m;
    rstd[j] = rsqrtf(v + 1e-5f);
}

// ---------------- normalize + tanh ----------------
__global__ __launch_bounds__(256) void knorm(const float* __restrict__ outb,
                                             const float* __restrict__ mean,
                                             const float* __restrict__ rstd,
                                             float* __restrict__ xn) {
    int idx = blockIdx.x * blockDim.x + threadIdx.x;
    int c = (idx & 31) * 4;
    float4 v = ((const float4*)outb)[idx];
    float4 mn = *(const float4*)(mean + c);
    float4 rs = *(const float4*)(rstd + c);
    float4 o;
    o.x = tanhf((v.x - mn.x) * rs.x);
    o.y = tanhf((v.y - mn.y) * rs.y);
    o.z = tanhf((v.z - mn.z) * rs.z);
    o.w = tanhf((v.w - mn.w) * rs.w);
    ((float4*)xn)[idx] = o;
}

// ---------------- relation transform: rn = r @ w ----------------
__global__ void krel(const float* __restrict__ r, const float* __restrict__ w,
                     float* __restrict__ rn) {
    __shared__ float sr[Dd];
    int j = threadIdx.x, row = blockIdx.x;
    sr[j] = r[row * Dd + j];
    __syncthreads();
    float acc = 0.f;
    for (int k = 0; k < Dd; k++) acc += sr[k] * w[k * Dd + j];
    rn[row * Dd + j] = acc;
}

extern "C" void kernel_launch(void* const* d_in, const int* in_sizes, int n_in,
                              void* d_out, int out_size, void* d_ws, size_t ws_size,
                              hipStream_t stream) {
    const float* x0      = (const float*)d_in[0];
    const float* r0      = (const float*)d_in[1];
    const float* w_in    = (const float*)d_in[2];
    const float* w_out   = (const float*)d_in[3];
    const float* w_loop  = (const float*)d_in[4];
    const float* w_rel   = (const float*)d_in[5];
    const float* looprel = (const float*)d_in[6];
    const float* bias    = (const float*)d_in[7];
    const int* esrc = (const int*)d_in[8];
    const int* edst = (const int*)d_in[9];
    const int* etyp = (const int*)d_in[10];
    float* outp = (float*)d_out;

    float* ws = (float*)d_ws;
    float* aggin   = ws;                       // ND
    float* aggout  = ws + (size_t)ND;          // ND
    float* x1      = ws + 2 * (size_t)ND;      // ND
    float* fp      = ws + 3 * (size_t)ND;
    float* dinv_s  = fp;           fp += Nn;
    float* dinv_d  = fp;           fp += Nn;
    float* colsum  = fp;           fp += Dd;
    float* colsumsq= fp;           fp += Dd;
    float* meanb   = fp;           fp += Dd;
    float* rstdb   = fp;           fp += Dd;
    float* r1      = fp;           fp += Rr * Dd;
    float* norm_s  = fp;           fp += Ee;
    float* norm_d  = fp;           fp += Ee;
    int* ip = (int*)fp;
    int* cnt_s  = ip;  ip += Nn;
    int* cnt_d  = ip;  ip += Nn;
    int* off_s  = ip;  ip += Nn + 1;
    int* off_d  = ip;  ip += Nn + 1;
    int* cur_s  = ip;  ip += Nn;
    int* cur_d  = ip;  ip += Nn;
    int* bsum_s = ip;  ip += 128;
    int* bsum_d = ip;  ip += 128;
    int* pack_s = ip;  ip += Ee;
    int* pack_d = ip;  ip += Ee;

    // ---- CSR build (edge lists are call-invariant; rebuilt every call) ----
    kzeroi<<<256, 256, 0, stream>>>(cnt_s, 2 * Nn);                 // cnt_s+cnt_d contiguous
    khist<<<(Ee + 255) / 256, 256, 0, stream>>>(esrc, edst, cnt_s, cnt_d, Ee);
    kdinv<<<(Nn + 255) / 256, 256, 0, stream>>>(cnt_s, cnt_d, dinv_s, dinv_d, Nn);
    kscan1<<<NBLK, 256, 0, stream>>>(cnt_s, off_s, bsum_s, Nn);
    kscan2<<<1, 128, 0, stream>>>(bsum_s, off_s, Nn, NBLK);
    kscan3<<<(Nn + 255) / 256, 256, 0, stream>>>(off_s, bsum_s, Nn);
    kscan1<<<NBLK, 256, 0, stream>>>(cnt_d, off_d, bsum_d, Nn);
    kscan2<<<1, 128, 0, stream>>>(bsum_d, off_d, Nn, NBLK);
    kscan3<<<(Nn + 255) / 256, 256, 0, stream>>>(off_d, bsum_d, Nn);
    kcopyi<<<(Nn + 255) / 256, 256, 0, stream>>>(off_s, cur_s, Nn);
    kcopyi<<<(Nn + 255) / 256, 256, 0, stream>>>(off_d, cur_d, Nn);
    kscatter<<<(Ee + 255) / 256, 256, 0, stream>>>(esrc, edst, etyp, dinv_s, dinv_d,
                                                   cur_s, cur_d, pack_s, norm_s,
                                                   pack_d, norm_d, Ee);

    for (int l = 0; l < 2; l++) {
        const float* xc = l ? x1 : x0;
        const float* rc = l ? r1 : r0;
        float* xn = l ? outp : x1;
        float* rn = l ? (outp + (size_t)ND) : r1;

        kzerof<<<1, 256, 0, stream>>>(colsum, 2 * Dd);
        kgather<<<(Nn + 3) / 4, 256, 0, stream>>>(off_s, pack_s, norm_s, xc, rc, aggin);
        kgather<<<(Nn + 3) / 4, 256, 0, stream>>>(off_d, pack_d, norm_d, xc, rc, aggout);
        kmm<<<Nn / TM, 256, 0, stream>>>(aggin, aggout, xc,
                                         w_in + l * Dd * Dd, w_out + l * Dd * Dd,
                                         w_loop + l * Dd * Dd, looprel + l * Dd,
                                         bias + l * Dd, aggin /*in-place out*/,
                                         colsum, colsumsq);
        kstats<<<1, Dd, 0, stream>>>(colsum, colsumsq, meanb, rstdb);
        knorm<<<ND / 4 / 256, 256, 0, stream>>>(aggin, meanb, rstdb, xn);
        krel<<<Rr, Dd, 0, stream>>>(rc, w_rel + l * Dd * Dd, rn);
    }
}

// Round 4
// 543.796 us; speedup vs baseline: 2.5414x; 1.6462x over previous
//
#include <hip/hip_runtime.h>
#include <math.h>

#define Nn 100000
#define Ee 500000
#define Dd 128
#define Rr 10
#define ND (Nn * Dd)
#define SCAN_CHUNK 1024
#define NBLK ((Nn + SCAN_CHUNK - 1) / SCAN_CHUNK)   // 98
#define LDK 136   // padded LDS row stride (fp16 elems): 272B rows -> 2-way bank alias (free)

typedef _Float16 half_t;
typedef __attribute__((ext_vector_type(8))) _Float16 half8;
typedef __attribute__((ext_vector_type(4))) float f32x4;
typedef unsigned short ushort;
typedef unsigned int uint;

union H2 { uint u; _Float16 h[2]; };
union H8 { uint4 q; _Float16 h[8]; };

__device__ __forceinline__ void atomAddF(float* p, float v) {
    unsafeAtomicAdd(p, v);   // HW global_atomic_add_f32
}

// ---------------- zero fill ----------------
__global__ void kzeroi(int* p, int n) {
    int i = blockIdx.x * blockDim.x + threadIdx.x;
    int stride = gridDim.x * blockDim.x;
    for (; i < n; i += stride) p[i] = 0;
}
__global__ void kzerof(float* p, int n) {
    int i = blockIdx.x * blockDim.x + threadIdx.x;
    int stride = gridDim.x * blockDim.x;
    for (; i < n; i += stride) p[i] = 0.f;
}

// ---------------- CSR build ----------------
__global__ void khist(const int* __restrict__ src, const int* __restrict__ dst,
                      int* cnt_s, int* cnt_d, int ne) {
    int e = blockIdx.x * blockDim.x + threadIdx.x;
    if (e < ne) {
        atomicAdd(&cnt_s[src[e]], 1);
        atomicAdd(&cnt_d[dst[e]], 1);
    }
}

__global__ void kdinv(const int* __restrict__ cnt_s, const int* __restrict__ cnt_d,
                      float* dinv_s, float* dinv_d, int n) {
    int i = blockIdx.x * blockDim.x + threadIdx.x;
    if (i < n) {
        int a = cnt_s[i];
        dinv_s[i] = (a > 0) ? rsqrtf((float)a) : 0.f;
        int b = cnt_d[i];
        dinv_d[i] = (b > 0) ? rsqrtf((float)b) : 0.f;
    }
}

__global__ __launch_bounds__(256) void kscan1(const int* __restrict__ cnt,
                                              int* off, int* bsum, int n) {
    __shared__ int s[256];
    int tid = threadIdx.x;
    int base = blockIdx.x * SCAN_CHUNK + tid * 4;
    int v[4], sum = 0;
#pragma unroll
    for (int q = 0; q < 4; q++) {
        v[q] = (base + q < n) ? cnt[base + q] : 0;
        sum += v[q];
    }
    s[tid] = sum;
    __syncthreads();
#pragma unroll
    for (int ofs = 1; ofs < 256; ofs <<= 1) {
        int t = (tid >= ofs) ? s[tid - ofs] : 0;
        __syncthreads();
        s[tid] += t;
        __syncthreads();
    }
    if (tid == 255) bsum[blockIdx.x] = s[255];
    int run = s[tid] - sum;
#pragma unroll
    for (int q = 0; q < 4; q++) {
        if (base + q < n) off[base + q] = run;
        run += v[q];
    }
}

__global__ __launch_bounds__(128) void kscan2(int* bsum, int* off, int n, int nb) {
    __shared__ int s[128];
    int tid = threadIdx.x;
    int v = (tid < nb) ? bsum[tid] : 0;
    s[tid] = v;
    __syncthreads();
#pragma unroll
    for (int ofs = 1; ofs < 128; ofs <<= 1) {
        int t = (tid >= ofs) ? s[tid - ofs] : 0;
        __syncthreads();
        s[tid] += t;
        __syncthreads();
    }
    if (tid < nb) bsum[tid] = s[tid] - v;
    if (tid == 127) off[n] = s[127];
}

__global__ void kscan3(int* off, const int* __restrict__ bsum, int n) {
    int i = blockIdx.x * blockDim.x + threadIdx.x;
    if (i < n) off[i] += bsum[i >> 10];
}

__global__ void kcopyi(const int* __restrict__ a, int* b, int n) {
    int i = blockIdx.x * blockDim.x + threadIdx.x;
    if (i < n) b[i] = a[i];
}

__global__ void kscatter(const int* __restrict__ src, const int* __restrict__ dst,
                         const int* __restrict__ typ,
                         const float* __restrict__ dinv_s, const float* __restrict__ dinv_d,
                         int* cur_s, int* cur_d,
                         int* pack_s, float* norm_s, int* pack_d, float* norm_d, int ne) {
    int e = blockIdx.x * blockDim.x + threadIdx.x;
    if (e >= ne) return;
    int s = src[e], d = dst[e], t = typ[e];
    int ps = atomicAdd(&cur_s[s], 1);
    pack_s[ps] = (d << 4) | t;
    norm_s[ps] = dinv_s[s] * dinv_s[d];
    int pd = atomicAdd(&cur_d[d], 1);
    pack_d[pd] = (s << 4) | t;
    norm_d[pd] = dinv_d[d] * dinv_d[s];
}

// ---------------- layer-0 prep: xb = f16(x0), xlb = f16(x0 * looprel0) ----------------
__global__ __launch_bounds__(256) void kxl0(const float* __restrict__ x,
                                            const float* __restrict__ lr,
                                            half_t* __restrict__ xb,
                                            half_t* __restrict__ xlb) {
    int idx = blockIdx.x * 256 + threadIdx.x;    // over ND/8
    int base = idx * 8;
    int k = base & 127;
    float4 v0 = *(const float4*)(x + base);
    float4 v1 = *(const float4*)(x + base + 4);
    float4 l0 = *(const float4*)(lr + k);
    float4 l1 = *(const float4*)(lr + k + 4);
    H8 xo, xl;
    xo.h[0] = (half_t)v0.x; xo.h[1] = (half_t)v0.y; xo.h[2] = (half_t)v0.z; xo.h[3] = (half_t)v0.w;
    xo.h[4] = (half_t)v1.x; xo.h[5] = (half_t)v1.y; xo.h[6] = (half_t)v1.z; xo.h[7] = (half_t)v1.w;
    xl.h[0] = (half_t)(v0.x * l0.x); xl.h[1] = (half_t)(v0.y * l0.y);
    xl.h[2] = (half_t)(v0.z * l0.z); xl.h[3] = (half_t)(v0.w * l0.w);
    xl.h[4] = (half_t)(v1.x * l1.x); xl.h[5] = (half_t)(v1.y * l1.y);
    xl.h[6] = (half_t)(v1.z * l1.z); xl.h[7] = (half_t)(v1.w * l1.w);
    *(uint4*)(xb + base) = xo.q;
    *(uint4*)(xlb + base) = xl.q;
}

// ---------------- W prep: Wt[p][n][k] = f16(W_p[k][n]) ----------------
__global__ void kwprep(const float* __restrict__ Win, const float* __restrict__ Wout,
                       const float* __restrict__ Wloop, half_t* __restrict__ Wt) {
    int idx = blockIdx.x * 256 + threadIdx.x;   // 3*16384
    int p = idx >> 14, rem = idx & 16383;
    int n = rem >> 7, k = rem & 127;
    const float* W = (p == 0) ? Win : ((p == 1) ? Wout : Wloop);
    Wt[idx] = (half_t)W[k * 128 + n];
}

// ---------------- gather-side aggregation (both CSRs in one grid), fp16 out ----------------
__global__ __launch_bounds__(256) void kgather(
    const int* __restrict__ off_s, const int* __restrict__ pack_s, const float* __restrict__ nrm_s,
    const int* __restrict__ off_d, const int* __restrict__ pack_d, const float* __restrict__ nrm_d,
    const half_t* __restrict__ xb, const float* __restrict__ rel,
    half_t* __restrict__ aggin, half_t* __restrict__ aggout, int gb) {
    int blk = blockIdx.x;
    const int *off, *pack; const float* nrm; half_t* agg;
    if (blk < gb) { off = off_s; pack = pack_s; nrm = nrm_s; agg = aggin; }
    else { blk -= gb; off = off_d; pack = pack_d; nrm = nrm_d; agg = aggout; }
    int node = (blk << 2) | (threadIdx.x >> 6);
    if (node >= Nn) return;
    int lane = threadIdx.x & 63;
    int b = off[node], e = off[node + 1];
    const uint* x2 = (const uint*)xb;        // 2 fp16 per uint
    const float2* r2 = (const float2*)rel;
    float accx = 0.f, accy = 0.f;
    int i = b;
    for (; i + 1 < e; i += 2) {              // 2-way unroll: overlap the two x-row loads
        int p0 = pack[i], p1 = pack[i + 1];
        float w0 = nrm[i], w1 = nrm[i + 1];
        H2 xv0, xv1;
        xv0.u = x2[(p0 >> 4) * 64 + lane];
        xv1.u = x2[(p1 >> 4) * 64 + lane];
        float2 rv0 = r2[(p0 & 15) * 64 + lane];
        float2 rv1 = r2[(p1 & 15) * 64 + lane];
        accx += (float)xv0.h[0] * rv0.x * w0;
        accy += (float)xv0.h[1] * rv0.y * w0;
        accx += (float)xv1.h[0] * rv1.x * w1;
        accy += (float)xv1.h[1] * rv1.y * w1;
    }
    if (i < e) {
        int p = pack[i];
        float w = nrm[i];
        H2 xv; xv.u = x2[(p >> 4) * 64 + lane];
        float2 rv = r2[(p & 15) * 64 + lane];
        accx += (float)xv.h[0] * rv.x * w;
        accy += (float)xv.h[1] * rv.y * w;
    }
    H2 o;
    o.h[0] = (half_t)accx; o.h[1] = (half_t)accy;
    ((uint*)agg)[node * 64 + lane] = o.u;
}

// ---------------- MFMA GEMM: out = ([aggin|aggout|xl] @ Wt^T)/3 + bias, + BN col stats ----
__global__ __launch_bounds__(256) void kmm(
    const half_t* __restrict__ aggin, const half_t* __restrict__ aggout,
    const half_t* __restrict__ xlb, const half_t* __restrict__ Wt,
    const float* __restrict__ bias, float* __restrict__ out,
    float* colsum, float* colsumsq) {
    __shared__ half_t sW[128 * LDK];     // 34.8 KB, sW[n*LDK + k]
    const int tid = threadIdx.x;
    const int wv = tid >> 6;
    const int lane = tid & 63;
    const int col = lane & 15;
    const int quad = lane >> 4;
    const int m0 = blockIdx.x * 128;
    const int rowbase = m0 + wv * 32;

    f32x4 acc[2][8];
#pragma unroll
    for (int m = 0; m < 2; m++)
#pragma unroll
        for (int j = 0; j < 8; j++) acc[m][j] = (f32x4){0.f, 0.f, 0.f, 0.f};

    const half_t* Ap[3] = {aggin, aggout, xlb};
    int r0 = rowbase + col;
    int r1 = r0 + 16;
    int r0c = (r0 < Nn) ? r0 : (Nn - 1);   // clamp; clamped subtiles are never stored
    int r1c = (r1 < Nn) ? r1 : (Nn - 1);

    for (int p = 0; p < 3; p++) {
        __syncthreads();
        {   // stage W phase tile: 2048 chunks of 8 fp16, padded rows
            const half8* Wg = (const half8*)(Wt + p * 16384);
#pragma unroll
            for (int i = 0; i < 8; i++) {
                int c = tid + i * 256;          // 0..2047
                int n = c >> 4, ko = (c & 15) * 8;
                *(half8*)(sW + n * LDK + ko) = Wg[c];
            }
        }
        __syncthreads();
        const half_t* A = Ap[p];
#pragma unroll
        for (int s = 0; s < 4; s++) {
            int ko = s * 32 + quad * 8;
            half8 a0 = *(const half8*)(A + r0c * Dd + ko);
            half8 a1 = *(const half8*)(A + r1c * Dd + ko);
#pragma unroll
            for (int j = 0; j < 8; j++) {
                half8 b = *(const half8*)(sW + (j * 16 + col) * LDK + ko);
                acc[0][j] = __builtin_amdgcn_mfma_f32_16x16x32_f16(a0, b, acc[0][j], 0, 0, 0);
                acc[1][j] = __builtin_amdgcn_mfma_f32_16x16x32_f16(a1, b, acc[1][j], 0, 0, 0);
            }
        }
    }

    // epilogue: scale+bias, store fp32, BN partial sums
    const float inv3 = 1.f / 3.f;
    float bcol[8], sum[8], ssq[8];
#pragma unroll
    for (int j = 0; j < 8; j++) {
        bcol[j] = bias[j * 16 + col];
        sum[j] = 0.f; ssq[j] = 0.f;
    }
#pragma unroll
    for (int m = 0; m < 2; m++) {
        int rb = rowbase + m * 16;
        if (rb < Nn) {
#pragma unroll
            for (int j = 0; j < 8; j++) {
#pragma unroll
                for (int r = 0; r < 4; r++) {
                    float v = acc[m][j][r] * inv3 + bcol[j];
                    out[(rb + quad * 4 + r) * Dd + j * 16 + col] = v;
                    sum[j] += v;
                    ssq[j] += v * v;
                }
            }
        }
    }
    // reduce across quads (lanes col, col+16, col+32, col+48)
#pragma unroll
    for (int j = 0; j < 8; j++) {
        sum[j] += __shfl_xor(sum[j], 16, 64);
        sum[j] += __shfl_xor(sum[j], 32, 64);
        ssq[j] += __shfl_xor(ssq[j], 16, 64);
        ssq[j] += __shfl_xor(ssq[j], 32, 64);
    }
    __syncthreads();                      // done with sW; reuse as float scratch
    float* sred = (float*)sW;             // [0:512)=sums, [512:1024)=sumsq
    if (quad == 0) {
#pragma unroll
        for (int j = 0; j < 8; j++) {
            sred[wv * 128 + j * 16 + col] = sum[j];
            sred[512 + wv * 128 + j * 16 + col] = ssq[j];
        }
    }
    __syncthreads();
    if (tid < 128) {
        float s = 0.f, s2 = 0.f;
#pragma unroll
        for (int w = 0; w < 4; w++) {
            s += sred[w * 128 + tid];
            s2 += sred[512 + w * 128 + tid];
        }
        atomAddF(&colsum[tid], s);
        atomAddF(&colsumsq[tid], s2);
    }
}

// ---------------- BN stats ----------------
__global__ void kstats(const float* __restrict__ colsum, const float* __restrict__ colsumsq,
                       float* mean, float* rstd) {
    int j = threadIdx.x;
    float m = colsum[j] * (1.f / (float)Nn);
    float v = colsumsq[j] * (1.f / (float)Nn) - m * m;
    mean[j] = m;
    rstd[j] = rsqrtf(v + 1e-5f);
}

// ---------------- normalize + tanh, layer 0: write fp16 x and fp16 x*looprel1 ------------
__global__ __launch_bounds__(256) void knorm0(const float* __restrict__ outb,
                                              const float* __restrict__ mean,
                                              const float* __restrict__ rstd,
                                              const float* __restrict__ lr,
                                              half_t* __restrict__ xb,
                                              half_t* __restrict__ xlb) {
    int idx = blockIdx.x * 256 + threadIdx.x;   // over ND/8
    int base = idx * 8;
    int k = base & 127;
    float4 v0 = *(const float4*)(outb + base);
    float4 v1 = *(const float4*)(outb + base + 4);
    float4 m0 = *(const float4*)(mean + k), m1 = *(const float4*)(mean + k + 4);
    float4 r0 = *(const float4*)(rstd + k), r1 = *(const float4*)(rstd + k + 4);
    float4 l0 = *(const float4*)(lr + k), l1 = *(const float4*)(lr + k + 4);
    float t[8];
    t[0] = tanhf((v0.x - m0.x) * r0.x); t[1] = tanhf((v0.y - m0.y) * r0.y);
    t[2] = tanhf((v0.z - m0.z) * r0.z); t[3] = tanhf((v0.w - m0.w) * r0.w);
    t[4] = tanhf((v1.x - m1.x) * r1.x); t[5] = tanhf((v1.y - m1.y) * r1.y);
    t[6] = tanhf((v1.z - m1.z) * r1.z); t[7] = tanhf((v1.w - m1.w) * r1.w);
    float ll[8] = {l0.x, l0.y, l0.z, l0.w, l1.x, l1.y, l1.z, l1.w};
    H8 xo, xl;
#pragma unroll
    for (int q = 0; q < 8; q++) { xo.h[q] = (half_t)t[q]; xl.h[q] = (half_t)(t[q] * ll[q]); }
    *(uint4*)(xb + base) = xo.q;
    *(uint4*)(xlb + base) = xl.q;
}

// ---------------- normalize + tanh, layer 1: write fp32 final output ----------------
__global__ __launch_bounds__(256) void knorm1(const float* __restrict__ outb,
                                              const float* __restrict__ mean,
                                              const float* __restrict__ rstd,
                                              float* __restrict__ xn) {
    int idx = blockIdx.x * blockDim.x + threadIdx.x;   // over ND/4
    int c = (idx & 31) * 4;
    float4 v = ((const float4*)outb)[idx];
    float4 mn = *(const float4*)(mean + c);
    float4 rs = *(const float4*)(rstd + c);
    float4 o;
    o.x = tanhf((v.x - mn.x) * rs.x);
    o.y = tanhf((v.y - mn.y) * rs.y);
    o.z = tanhf((v.z - mn.z) * rs.z);
    o.w = tanhf((v.w - mn.w) * rs.w);
    ((float4*)xn)[idx] = o;
}

// ---------------- relation transform: rn = r @ w (fp32) ----------------
__global__ void krel(const float* __restrict__ r, const float* __restrict__ w,
                     float* __restrict__ rn) {
    __shared__ float sr[Dd];
    int j = threadIdx.x, row = blockIdx.x;
    sr[j] = r[row * Dd + j];
    __syncthreads();
    float acc = 0.f;
    for (int k = 0; k < Dd; k++) acc += sr[k] * w[k * Dd + j];
    rn[row * Dd + j] = acc;
}

extern "C" void kernel_launch(void* const* d_in, const int* in_sizes, int n_in,
                              void* d_out, int out_size, void* d_ws, size_t ws_size,
                              hipStream_t stream) {
    const float* x0      = (const float*)d_in[0];
    const float* r0      = (const float*)d_in[1];
    const float* w_in    = (const float*)d_in[2];
    const float* w_out   = (const float*)d_in[3];
    const float* w_loop  = (const float*)d_in[4];
    const float* w_rel   = (const float*)d_in[5];
    const float* looprel = (const float*)d_in[6];
    const float* bias    = (const float*)d_in[7];
    const int* esrc = (const int*)d_in[8];
    const int* edst = (const int*)d_in[9];
    const int* etyp = (const int*)d_in[10];
    float* outp = (float*)d_out;

    // fp16 buffers first (16 B alignment for half8 loads)
    half_t* us = (half_t*)d_ws;
    half_t* aggin_h  = us;                       // ND
    half_t* aggout_h = us + (size_t)ND;          // ND
    half_t* xb       = us + 2 * (size_t)ND;      // ND
    half_t* xlb      = us + 3 * (size_t)ND;      // ND
    half_t* Wt       = us + 4 * (size_t)ND;      // 3*16384
    float* fp = (float*)(us + 4 * (size_t)ND + 3 * 16384);
    float* outbuf  = fp;           fp += (size_t)ND;
    float* dinv_s  = fp;           fp += Nn;
    float* dinv_d  = fp;           fp += Nn;
    float* colsum  = fp;           fp += Dd;
    float* colsumsq= fp;           fp += Dd;
    float* meanb   = fp;           fp += Dd;
    float* rstdb   = fp;           fp += Dd;
    float* r1      = fp;           fp += Rr * Dd;
    float* norm_s  = fp;           fp += Ee;
    float* norm_d  = fp;           fp += Ee;
    int* ip = (int*)fp;
    int* cnt_s  = ip;  ip += Nn;
    int* cnt_d  = ip;  ip += Nn;
    int* off_s  = ip;  ip += Nn + 1;
    int* off_d  = ip;  ip += Nn + 1;
    int* cur_s  = ip;  ip += Nn;
    int* cur_d  = ip;  ip += Nn;
    int* bsum_s = ip;  ip += 128;
    int* bsum_d = ip;  ip += 128;
    int* pack_s = ip;  ip += Ee;
    int* pack_d = ip;  ip += Ee;

    // ---- CSR build ----
    kzeroi<<<256, 256, 0, stream>>>(cnt_s, 2 * Nn);
    khist<<<(Ee + 255) / 256, 256, 0, stream>>>(esrc, edst, cnt_s, cnt_d, Ee);
    kdinv<<<(Nn + 255) / 256, 256, 0, stream>>>(cnt_s, cnt_d, dinv_s, dinv_d, Nn);
    kscan1<<<NBLK, 256, 0, stream>>>(cnt_s, off_s, bsum_s, Nn);
    kscan2<<<1, 128, 0, stream>>>(bsum_s, off_s, Nn, NBLK);
    kscan3<<<(Nn + 255) / 256, 256, 0, stream>>>(off_s, bsum_s, Nn);
    kscan1<<<NBLK, 256, 0, stream>>>(cnt_d, off_d, bsum_d, Nn);
    kscan2<<<1, 128, 0, stream>>>(bsum_d, off_d, Nn, NBLK);
    kscan3<<<(Nn + 255) / 256, 256, 0, stream>>>(off_d, bsum_d, Nn);
    kcopyi<<<(Nn + 255) / 256, 256, 0, stream>>>(off_s, cur_s, Nn);
    kcopyi<<<(Nn + 255) / 256, 256, 0, stream>>>(off_d, cur_d, Nn);
    kscatter<<<(Ee + 255) / 256, 256, 0, stream>>>(esrc, edst, etyp, dinv_s, dinv_d,
                                                   cur_s, cur_d, pack_s, norm_s,
                                                   pack_d, norm_d, Ee);
    // layer-0 fp16 prep
    kxl0<<<ND / 8 / 256, 256, 0, stream>>>(x0, looprel, xb, xlb);

    const int gb = (Nn + 3) / 4;
    for (int l = 0; l < 2; l++) {
        const float* rc = l ? r1 : r0;
        float* rn = l ? (outp + (size_t)ND) : r1;

        kzerof<<<1, 256, 0, stream>>>(colsum, 2 * Dd);
        kwprep<<<3 * 16384 / 256, 256, 0, stream>>>(w_in + l * Dd * Dd, w_out + l * Dd * Dd,
                                                    w_loop + l * Dd * Dd, Wt);
        kgather<<<2 * gb, 256, 0, stream>>>(off_s, pack_s, norm_s, off_d, pack_d, norm_d,
                                            xb, rc, aggin_h, aggout_h, gb);
        kmm<<<(Nn + 127) / 128, 256, 0, stream>>>(aggin_h, aggout_h, xlb, Wt,
                                                  bias + l * Dd, outbuf, colsum, colsumsq);
        kstats<<<1, Dd, 0, stream>>>(colsum, colsumsq, meanb, rstdb);
        if (l == 0) {
            knorm0<<<ND / 8 / 256, 256, 0, stream>>>(outbuf, meanb, rstdb, looprel + Dd, xb, xlb);
        } else {
            knorm1<<<ND / 4 / 256, 256, 0, stream>>>(outbuf, meanb, rstdb, outp);
        }
        krel<<<Rr, Dd, 0, stream>>>(rc, w_rel + l * Dd * Dd, rn);
    }
}

// Round 5
// 490.284 us; speedup vs baseline: 2.8187x; 1.1091x over previous
//
#include <hip/hip_runtime.h>
#include <math.h>

#define Nn 100000
#define Ee 500000
#define Dd 128
#define Rr 10
#define ND (Nn * Dd)
#define SCAN_CHUNK 1024
#define NBLK ((Nn + SCAN_CHUNK - 1) / SCAN_CHUNK)   // 98
#define LDK 136   // padded LDS row stride (fp16 elems)
#define EPSF 1e-5f

typedef _Float16 half_t;
typedef __attribute__((ext_vector_type(8))) _Float16 half8;
typedef __attribute__((ext_vector_type(4))) float f32x4;
typedef unsigned short ushort;
typedef unsigned int uint;
typedef unsigned long long u64;

union H2 { uint u; _Float16 h[2]; };
union H4 { u64 u; _Float16 h[4]; };
union H8 { uint4 q; _Float16 h[8]; };

__device__ __forceinline__ void atomAddF(float* p, float v) {
    unsafeAtomicAdd(p, v);   // HW global_atomic_add_f32
}

// ---------------- zero fill (cnt_s, cnt_d, colsum sets) ----------------
__global__ void kzeroi(int* p, int n) {
    int i = blockIdx.x * blockDim.x + threadIdx.x;
    int stride = gridDim.x * blockDim.x;
    for (; i < n; i += stride) p[i] = 0;
}

// ---------------- CSR build ----------------
__global__ void khist(const int* __restrict__ src, const int* __restrict__ dst,
                      int* cnt_s, int* cnt_d, int ne) {
    int e = blockIdx.x * blockDim.x + threadIdx.x;
    if (e < ne) {
        atomicAdd(&cnt_s[src[e]], 1);
        atomicAdd(&cnt_d[dst[e]], 1);
    }
}

// dual-direction local scan + dinv
__global__ __launch_bounds__(256) void kscan1(
    const int* __restrict__ cnt_s, const int* __restrict__ cnt_d,
    int* off_s, int* off_d, int* bsum_s, int* bsum_d,
    float* dinv_s, float* dinv_d) {
    int dir = blockIdx.x >= NBLK;
    int lb = blockIdx.x - dir * NBLK;
    const int* cnt = dir ? cnt_d : cnt_s;
    int* off = dir ? off_d : off_s;
    int* bsum = dir ? bsum_d : bsum_s;
    float* dinv = dir ? dinv_d : dinv_s;
    __shared__ int s[256];
    int tid = threadIdx.x;
    int base = lb * SCAN_CHUNK + tid * 4;
    int v[4], sum = 0;
#pragma unroll
    for (int q = 0; q < 4; q++) {
        int c = (base + q < Nn) ? cnt[base + q] : 0;
        v[q] = c;
        sum += c;
        if (base + q < Nn) dinv[base + q] = (c > 0) ? rsqrtf((float)c) : 0.f;
    }
    s[tid] = sum;
    __syncthreads();
#pragma unroll
    for (int ofs = 1; ofs < 256; ofs <<= 1) {
        int t = (tid >= ofs) ? s[tid - ofs] : 0;
        __syncthreads();
        s[tid] += t;
        __syncthreads();
    }
    if (tid == 255) bsum[lb] = s[255];
    int run = s[tid] - sum;
#pragma unroll
    for (int q = 0; q < 4; q++) {
        if (base + q < Nn) off[base + q] = run;
        run += v[q];
    }
}

// dual-direction block-sum scan (2 blocks)
__global__ __launch_bounds__(128) void kscan2(int* bsum_s, int* bsum_d,
                                              int* off_s, int* off_d) {
    int dir = blockIdx.x;
    int* bsum = dir ? bsum_d : bsum_s;
    int* off = dir ? off_d : off_s;
    __shared__ int s[128];
    int tid = threadIdx.x;
    int v = (tid < NBLK) ? bsum[tid] : 0;
    s[tid] = v;
    __syncthreads();
#pragma unroll
    for (int ofs = 1; ofs < 128; ofs <<= 1) {
        int t = (tid >= ofs) ? s[tid - ofs] : 0;
        __syncthreads();
        s[tid] += t;
        __syncthreads();
    }
    if (tid < NBLK) bsum[tid] = s[tid] - v;
    if (tid == 127) off[Nn] = s[127];
}

// add block bases + write cursor copies
__global__ void kscan3(int* off_s, int* off_d, const int* __restrict__ bsum_s,
                       const int* __restrict__ bsum_d, int* cur_s, int* cur_d) {
    int idx = blockIdx.x * blockDim.x + threadIdx.x;
    if (idx >= 2 * Nn) return;
    int dir = idx >= Nn;
    int i = idx - dir * Nn;
    int* off = dir ? off_d : off_s;
    const int* bsum = dir ? bsum_d : bsum_s;
    int* cur = dir ? cur_d : cur_s;
    int o = off[i] + bsum[i >> 10];
    off[i] = o;
    cur[i] = o;
}

__global__ void kscatter(const int* __restrict__ src, const int* __restrict__ dst,
                         const int* __restrict__ typ,
                         const float* __restrict__ dinv_s, const float* __restrict__ dinv_d,
                         int* cur_s, int* cur_d,
                         int* pack_s, float* norm_s, int* pack_d, float* norm_d, int ne) {
    int e = blockIdx.x * blockDim.x + threadIdx.x;
    if (e >= ne) return;
    int s = src[e], d = dst[e], t = typ[e];
    int ps = atomicAdd(&cur_s[s], 1);
    pack_s[ps] = (d << 4) | t;
    norm_s[ps] = dinv_s[s] * dinv_s[d];
    int pd = atomicAdd(&cur_d[d], 1);
    pack_d[pd] = (s << 4) | t;
    norm_d[pd] = dinv_d[d] * dinv_d[s];
}

// ---------------- mega-prep: xb/xlb cast | W cast+transpose (both layers) | rel chain ----
__global__ __launch_bounds__(256) void kprep(
    const float* __restrict__ x, const float* __restrict__ lr0,
    const float* __restrict__ w_in, const float* __restrict__ w_out,
    const float* __restrict__ w_loop, const float* __restrict__ w_rel,
    const float* __restrict__ r0,
    half_t* __restrict__ xb, half_t* __restrict__ xlb,
    half_t* __restrict__ Wt, float* __restrict__ r1, float* __restrict__ r2) {
    int blk = blockIdx.x;
    int tid = threadIdx.x;
    if (blk < ND / 8 / 256) {
        // xb = f16(x0), xlb = f16(x0 * looprel0)
        int idx = blk * 256 + tid;
        int base = idx * 8;
        int k = base & 127;
        float4 v0 = *(const float4*)(x + base);
        float4 v1 = *(const float4*)(x + base + 4);
        float4 l0 = *(const float4*)(lr0 + k);
        float4 l1 = *(const float4*)(lr0 + k + 4);
        H8 xo, xl;
        xo.h[0] = (half_t)v0.x; xo.h[1] = (half_t)v0.y; xo.h[2] = (half_t)v0.z; xo.h[3] = (half_t)v0.w;
        xo.h[4] = (half_t)v1.x; xo.h[5] = (half_t)v1.y; xo.h[6] = (half_t)v1.z; xo.h[7] = (half_t)v1.w;
        xl.h[0] = (half_t)(v0.x * l0.x); xl.h[1] = (half_t)(v0.y * l0.y);
        xl.h[2] = (half_t)(v0.z * l0.z); xl.h[3] = (half_t)(v0.w * l0.w);
        xl.h[4] = (half_t)(v1.x * l1.x); xl.h[5] = (half_t)(v1.y * l1.y);
        xl.h[6] = (half_t)(v1.z * l1.z); xl.h[7] = (half_t)(v1.w * l1.w);
        *(uint4*)(xb + base) = xo.q;
        *(uint4*)(xlb + base) = xl.q;
    } else if (blk < ND / 8 / 256 + 384) {
        // Wt[l][p][n][k] = f16(W[l,p][k][n]) for both layers
        int idx = (blk - ND / 8 / 256) * 256 + tid;   // 0..98303
        int l = idx >= 49152;
        int rem = idx - l * 49152;
        int p = rem >> 14, r2i = rem & 16383;
        int n = r2i >> 7, k = r2i & 127;
        const float* W = (p == 0) ? (w_in + l * 16384)
                       : ((p == 1) ? (w_out + l * 16384) : (w_loop + l * 16384));
        Wt[idx] = (half_t)W[k * 128 + n];
    } else {
        // rel chain: r1 = r0 @ w_rel[0]; r2 = r1 @ w_rel[1]  (single block)
        __shared__ float sr[Rr * Dd];
        for (int i = tid; i < Rr * Dd; i += 256) sr[i] = r0[i];
        __syncthreads();
        for (int ph = 0; ph < 2; ph++) {
            const float* w = w_rel + ph * 16384;
            float o[5];
#pragma unroll
            for (int q = 0; q < 5; q++) {
                int oi = tid + q * 256;
                int row = oi >> 7, j = oi & 127;
                float acc = 0.f;
                for (int k = 0; k < 128; k++) acc += sr[row * 128 + k] * w[k * 128 + j];
                o[q] = acc;
            }
            __syncthreads();
            float* dst = ph ? r2 : r1;
#pragma unroll
            for (int q = 0; q < 5; q++) {
                int oi = tid + q * 256;
                sr[oi] = o[q];
                dst[oi] = o[q];
            }
            __syncthreads();
        }
    }
}

// ---------------- gather v2: 2 nodes/wave, 8B/lane, unroll 2 ----------------
__global__ __launch_bounds__(256) void kgather(
    const int* __restrict__ off_s, const int* __restrict__ pack_s, const float* __restrict__ nrm_s,
    const int* __restrict__ off_d, const int* __restrict__ pack_d, const float* __restrict__ nrm_d,
    const half_t* __restrict__ xb, const float* __restrict__ rel,
    half_t* __restrict__ aggin, half_t* __restrict__ aggout, int gb) {
    int blk = blockIdx.x;
    const int *off, *pack; const float* nrm; half_t* agg;
    if (blk < gb) { off = off_s; pack = pack_s; nrm = nrm_s; agg = aggin; }
    else { blk -= gb; off = off_d; pack = pack_d; nrm = nrm_d; agg = aggout; }
    int wv = threadIdx.x >> 6;
    int lane = threadIdx.x & 63;
    int half = lane >> 5;      // which node of the pair
    int hl = lane & 31;        // 8-byte chunk within row
    int node = blk * 8 + wv * 2 + half;
    bool valid = node < Nn;
    int nodec = valid ? node : (Nn - 1);
    int b = off[nodec];
    int e = off[nodec + 1];
    int n_it = valid ? (e - b) : 0;
    int other = __shfl(n_it, lane ^ 32, 64);
    int mx = n_it > other ? n_it : other;    // wave-uniform loop bound

    const u64* x4 = (const u64*)xb;
    const float4* r4 = (const float4*)rel;
    float a0 = 0.f, a1 = 0.f, a2 = 0.f, a3 = 0.f;

    int it = 0;
    for (; it + 1 < mx; it += 2) {
        bool c0 = it < n_it, c1 = it + 1 < n_it;
        int i0 = c0 ? (b + it) : 0;
        int i1 = c1 ? (b + it + 1) : 0;
        int p0 = pack[i0], p1 = pack[i1];
        float w0 = c0 ? nrm[i0] : 0.f;
        float w1 = c1 ? nrm[i1] : 0.f;
        H4 xv0, xv1;
        xv0.u = x4[(size_t)(p0 >> 4) * 32 + hl];
        xv1.u = x4[(size_t)(p1 >> 4) * 32 + hl];
        float4 rv0 = r4[(p0 & 15) * 32 + hl];
        float4 rv1 = r4[(p1 & 15) * 32 + hl];
        a0 += (float)xv0.h[0] * rv0.x * w0;
        a1 += (float)xv0.h[1] * rv0.y * w0;
        a2 += (float)xv0.h[2] * rv0.z * w0;
        a3 += (float)xv0.h[3] * rv0.w * w0;
        a0 += (float)xv1.h[0] * rv1.x * w1;
        a1 += (float)xv1.h[1] * rv1.y * w1;
        a2 += (float)xv1.h[2] * rv1.z * w1;
        a3 += (float)xv1.h[3] * rv1.w * w1;
    }
    if (it < mx) {
        bool c0 = it < n_it;
        int i0 = c0 ? (b + it) : 0;
        int p0 = pack[i0];
        float w0 = c0 ? nrm[i0] : 0.f;
        H4 xv0; xv0.u = x4[(size_t)(p0 >> 4) * 32 + hl];
        float4 rv0 = r4[(p0 & 15) * 32 + hl];
        a0 += (float)xv0.h[0] * rv0.x * w0;
        a1 += (float)xv0.h[1] * rv0.y * w0;
        a2 += (float)xv0.h[2] * rv0.z * w0;
        a3 += (float)xv0.h[3] * rv0.w * w0;
    }
    if (valid) {
        H4 o;
        o.h[0] = (half_t)a0; o.h[1] = (half_t)a1;
        o.h[2] = (half_t)a2; o.h[3] = (half_t)a3;
        ((u64*)agg)[(size_t)node * 32 + hl] = o.u;
    }
}

// ---------------- MFMA GEMM + bias + BN col stats, fp16 out ----------------
__global__ __launch_bounds__(256) void kmm(
    const half_t* __restrict__ aggin, const half_t* __restrict__ aggout,
    const half_t* __restrict__ xlb, const half_t* __restrict__ Wt,
    const float* __restrict__ bias, half_t* __restrict__ out,
    float* colsum, float* colsumsq) {
    __shared__ half_t sW[128 * LDK];
    const int tid = threadIdx.x;
    const int wv = tid >> 6;
    const int lane = tid & 63;
    const int col = lane & 15;
    const int quad = lane >> 4;
    const int m0 = blockIdx.x * 128;
    const int rowbase = m0 + wv * 32;

    f32x4 acc[2][8];
#pragma unroll
    for (int m = 0; m < 2; m++)
#pragma unroll
        for (int j = 0; j < 8; j++) acc[m][j] = (f32x4){0.f, 0.f, 0.f, 0.f};

    const half_t* Ap[3] = {aggin, aggout, xlb};
    int r0 = rowbase + col;
    int r1 = r0 + 16;
    int r0c = (r0 < Nn) ? r0 : (Nn - 1);
    int r1c = (r1 < Nn) ? r1 : (Nn - 1);

    for (int p = 0; p < 3; p++) {
        __syncthreads();
        {
            const half8* Wg = (const half8*)(Wt + p * 16384);
#pragma unroll
            for (int i = 0; i < 8; i++) {
                int c = tid + i * 256;
                int n = c >> 4, ko = (c & 15) * 8;
                *(half8*)(sW + n * LDK + ko) = Wg[c];
            }
        }
        __syncthreads();
        const half_t* A = Ap[p];
#pragma unroll
        for (int s = 0; s < 4; s++) {
            int ko = s * 32 + quad * 8;
            half8 va0 = *(const half8*)(A + r0c * Dd + ko);
            half8 va1 = *(const half8*)(A + r1c * Dd + ko);
#pragma unroll
            for (int j = 0; j < 8; j++) {
                half8 vb = *(const half8*)(sW + (j * 16 + col) * LDK + ko);
                acc[0][j] = __builtin_amdgcn_mfma_f32_16x16x32_f16(va0, vb, acc[0][j], 0, 0, 0);
                acc[1][j] = __builtin_amdgcn_mfma_f32_16x16x32_f16(va1, vb, acc[1][j], 0, 0, 0);
            }
        }
    }

    const float inv3 = 1.f / 3.f;
    float bcol[8], sum[8], ssq[8];
#pragma unroll
    for (int j = 0; j < 8; j++) {
        bcol[j] = bias[j * 16 + col];
        sum[j] = 0.f; ssq[j] = 0.f;
    }
#pragma unroll
    for (int m = 0; m < 2; m++) {
        int rb = rowbase + m * 16;
        if (rb < Nn) {
#pragma unroll
            for (int j = 0; j < 8; j++) {
#pragma unroll
                for (int r = 0; r < 4; r++) {
                    float v = acc[m][j][r] * inv3 + bcol[j];
                    out[(rb + quad * 4 + r) * Dd + j * 16 + col] = (half_t)v;
                    sum[j] += v;
                    ssq[j] += v * v;
                }
            }
        }
    }
#pragma unroll
    for (int j = 0; j < 8; j++) {
        sum[j] += __shfl_xor(sum[j], 16, 64);
        sum[j] += __shfl_xor(sum[j], 32, 64);
        ssq[j] += __shfl_xor(ssq[j], 16, 64);
        ssq[j] += __shfl_xor(ssq[j], 32, 64);
    }
    __syncthreads();
    float* sred = (float*)sW;
    if (quad == 0) {
#pragma unroll
        for (int j = 0; j < 8; j++) {
            sred[wv * 128 + j * 16 + col] = sum[j];
            sred[512 + wv * 128 + j * 16 + col] = ssq[j];
        }
    }
    __syncthreads();
    if (tid < 128) {
        float s = 0.f, s2 = 0.f;
#pragma unroll
        for (int w = 0; w < 4; w++) {
            s += sred[w * 128 + tid];
            s2 += sred[512 + w * 128 + tid];
        }
        atomAddF(&colsum[tid], s);
        atomAddF(&colsumsq[tid], s2);
    }
}

// ---------------- norm+tanh layer0 (stats inline): write fp16 xb, xlb ----------------
__global__ __launch_bounds__(256) void knorm0(const half_t* __restrict__ outh,
                                              const float* __restrict__ colsum,
                                              const float* __restrict__ colsumsq,
                                              const float* __restrict__ lr,
                                              half_t* __restrict__ xb,
                                              half_t* __restrict__ xlb) {
    __shared__ float sm[128], srs[128];
    int tid = threadIdx.x;
    if (tid < 128) {
        float m = colsum[tid] * (1.f / (float)Nn);
        float v = colsumsq[tid] * (1.f / (float)Nn) - m * m;
        sm[tid] = m;
        srs[tid] = rsqrtf(v + EPSF);
    }
    __syncthreads();
    int idx = blockIdx.x * 256 + tid;
    int base = idx * 8;
    int k = base & 127;
    H8 v; v.q = *(const uint4*)(outh + base);
    H8 xo, xl;
#pragma unroll
    for (int q = 0; q < 8; q++) {
        float t = tanhf(((float)v.h[q] - sm[k + q]) * srs[k + q]);
        xo.h[q] = (half_t)t;
        xl.h[q] = (half_t)(t * lr[k + q]);
    }
    *(uint4*)(xb + base) = xo.q;
    *(uint4*)(xlb + base) = xl.q;
}

// ---------------- norm+tanh layer1 (stats inline): write fp32 final ----------------
__global__ __launch_bounds__(256) void knorm1(const half_t* __restrict__ outh,
                                              const float* __restrict__ colsum,
                                              const float* __restrict__ colsumsq,
                                              float* __restrict__ xn) {
    __shared__ float sm[128], srs[128];
    int tid = threadIdx.x;
    if (tid < 128) {
        float m = colsum[tid] * (1.f / (float)Nn);
        float v = colsumsq[tid] * (1.f / (float)Nn) - m * m;
        sm[tid] = m;
        srs[tid] = rsqrtf(v + EPSF);
    }
    __syncthreads();
    int idx = blockIdx.x * 256 + tid;
    int base = idx * 8;
    int k = base & 127;
    H8 v; v.q = *(const uint4*)(outh + base);
    float4 o0, o1;
    o0.x = tanhf(((float)v.h[0] - sm[k + 0]) * srs[k + 0]);
    o0.y = tanhf(((float)v.h[1] - sm[k + 1]) * srs[k + 1]);
    o0.z = tanhf(((float)v.h[2] - sm[k + 2]) * srs[k + 2]);
    o0.w = tanhf(((float)v.h[3] - sm[k + 3]) * srs[k + 3]);
    o1.x = tanhf(((float)v.h[4] - sm[k + 4]) * srs[k + 4]);
    o1.y = tanhf(((float)v.h[5] - sm[k + 5]) * srs[k + 5]);
    o1.z = tanhf(((float)v.h[6] - sm[k + 6]) * srs[k + 6]);
    o1.w = tanhf(((float)v.h[7] - sm[k + 7]) * srs[k + 7]);
    *(float4*)(xn + base) = o0;
    *(float4*)(xn + base + 4) = o1;
}

extern "C" void kernel_launch(void* const* d_in, const int* in_sizes, int n_in,
                              void* d_out, int out_size, void* d_ws, size_t ws_size,
                              hipStream_t stream) {
    const float* x0      = (const float*)d_in[0];
    const float* r0      = (const float*)d_in[1];
    const float* w_in    = (const float*)d_in[2];
    const float* w_out   = (const float*)d_in[3];
    const float* w_loop  = (const float*)d_in[4];
    const float* w_rel   = (const float*)d_in[5];
    const float* looprel = (const float*)d_in[6];
    const float* bias    = (const float*)d_in[7];
    const int* esrc = (const int*)d_in[8];
    const int* edst = (const int*)d_in[9];
    const int* etyp = (const int*)d_in[10];
    float* outp = (float*)d_out;

    // half region
    half_t* us = (half_t*)d_ws;
    half_t* aggin_h  = us;                        // ND
    half_t* aggout_h = us + (size_t)ND;           // ND
    half_t* xb       = us + 2 * (size_t)ND;       // ND
    half_t* xlb      = us + 3 * (size_t)ND;       // ND
    half_t* outh     = us + 4 * (size_t)ND;       // ND
    half_t* Wt       = us + 5 * (size_t)ND;       // 2*49152
    // float region
    float* fp = (float*)(us + 5 * (size_t)ND + 2 * 49152);
    float* dinv_s  = fp;   fp += Nn;
    float* dinv_d  = fp;   fp += Nn;
    float* r1      = fp;   fp += Rr * Dd;
    float* norm_s  = fp;   fp += Ee;
    float* norm_d  = fp;   fp += Ee;
    // int region (zero block first: cnt_s, cnt_d, colsums A+B)
    int* ip = (int*)fp;
    int* cnt_s  = ip;  ip += Nn;
    int* cnt_d  = ip;  ip += Nn;
    float* colsumA = (float*)ip;  ip += 2 * Dd;   // colsum + colsumsq, layer 0
    float* colsumB = (float*)ip;  ip += 2 * Dd;   // layer 1
    int* off_s  = ip;  ip += Nn + 1;
    int* off_d  = ip;  ip += Nn + 1;
    int* cur_s  = ip;  ip += Nn;
    int* cur_d  = ip;  ip += Nn;
    int* bsum_s = ip;  ip += 128;
    int* bsum_d = ip;  ip += 128;
    int* pack_s = ip;  ip += Ee;
    int* pack_d = ip;  ip += Ee;

    // 1: zero cnt_s+cnt_d+colsumA+colsumB (contiguous)
    kzeroi<<<256, 256, 0, stream>>>(cnt_s, 2 * Nn + 4 * Dd);
    // 2: histogram
    khist<<<(Ee + 255) / 256, 256, 0, stream>>>(esrc, edst, cnt_s, cnt_d, Ee);
    // 3-5: dual scans (+dinv, +cursor copy)
    kscan1<<<2 * NBLK, 256, 0, stream>>>(cnt_s, cnt_d, off_s, off_d, bsum_s, bsum_d,
                                         dinv_s, dinv_d);
    kscan2<<<2, 128, 0, stream>>>(bsum_s, bsum_d, off_s, off_d);
    kscan3<<<(2 * Nn + 255) / 256, 256, 0, stream>>>(off_s, off_d, bsum_s, bsum_d,
                                                     cur_s, cur_d);
    // 6: CSR scatter
    kscatter<<<(Ee + 255) / 256, 256, 0, stream>>>(esrc, edst, etyp, dinv_s, dinv_d,
                                                   cur_s, cur_d, pack_s, norm_s,
                                                   pack_d, norm_d, Ee);
    // 7: mega-prep (x cast | W cast both layers | rel chain r1,r2)
    kprep<<<ND / 8 / 256 + 384 + 1, 256, 0, stream>>>(
        x0, looprel, w_in, w_out, w_loop, w_rel, r0,
        xb, xlb, Wt, r1, outp + (size_t)ND);

    const int gb = (Nn + 7) / 8;
    for (int l = 0; l < 2; l++) {
        const float* rc = l ? r1 : r0;
        float* cs = l ? colsumB : colsumA;
        kgather<<<2 * gb, 256, 0, stream>>>(off_s, pack_s, norm_s, off_d, pack_d, norm_d,
                                            xb, rc, aggin_h, aggout_h, gb);
        kmm<<<(Nn + 127) / 128, 256, 0, stream>>>(aggin_h, aggout_h, xlb, Wt + l * 49152,
                                                  bias + l * Dd, outh, cs, cs + Dd);
        if (l == 0) {
            knorm0<<<ND / 8 / 256, 256, 0, stream>>>(outh, cs, cs + Dd, looprel + Dd, xb, xlb);
        } else {
            knorm1<<<ND / 8 / 256, 256, 0, stream>>>(outh, cs, cs + Dd, outp);
        }
    }
}